// Round 10
// baseline (256.573 us; speedup 1.0000x reference)
//
#include <hip/hip_runtime.h>

typedef unsigned short ushort_t;
typedef __attribute__((ext_vector_type(8))) short short8;
typedef __attribute__((ext_vector_type(4))) float f32x4;

#define AS1 __attribute__((address_space(1)))
#define AS3 __attribute__((address_space(3)))

__device__ __forceinline__ ushort_t f2bf(float f) {
  unsigned int u = __builtin_bit_cast(unsigned int, f);
  u += 0x7fffu + ((u >> 16) & 1u);            // round-to-nearest-even
  return (ushort_t)(u >> 16);
}

// pack two floats to bf16x2 (round-half-up fallback; HW cvt_pk when available)
__device__ __forceinline__ unsigned int pack_bf2(float a, float b) {
  unsigned int ua = __builtin_bit_cast(unsigned int, a) + 0x8000u;
  unsigned int ub = __builtin_bit_cast(unsigned int, b) + 0x8000u;
  return (ua >> 16) | (ub & 0xffff0000u);
}

#if defined(__has_builtin)
#if __has_builtin(__builtin_amdgcn_cvt_pk_bf16_f32)
#define HAVE_CVT_PK_BF16 1
#endif
#if __has_builtin(__builtin_amdgcn_exp2f)
#define HAVE_EXP2 1
#endif
#endif

__device__ __forceinline__ unsigned int pack2(float a, float b) {
#ifdef HAVE_CVT_PK_BF16
  typedef __attribute__((ext_vector_type(2))) __bf16 bf2_t;
  bf2_t r = __builtin_amdgcn_cvt_pk_bf16_f32(a, b);
  return __builtin_bit_cast(unsigned int, r);
#else
  return pack_bf2(a, b);
#endif
}

__device__ __forceinline__ float fast_exp2(float x) {
#ifdef HAVE_EXP2
  return __builtin_amdgcn_exp2f(x);
#else
  return exp2f(x);
#endif
}

__device__ __forceinline__ void load_lds16(const ushort_t* g, ushort_t* l) {
  __builtin_amdgcn_global_load_lds((AS1 void*)g, (AS3 void*)l, 16, 0, 0);
}

#define MFMA16(a, b, c) __builtin_amdgcn_mfma_f32_16x16x32_bf16((a), (b), (c), 0, 0, 0)
#define BAR() __builtin_amdgcn_s_barrier()
#define SCHEDB() __builtin_amdgcn_sched_barrier(0)
#define WAITV_(N) asm volatile("s_waitcnt vmcnt(" #N ")" ::: "memory")
#define WAITV(N) WAITV_(N)

// ---------------- fused prep: hs convert (blocks 0..4095) + wqkv transpose
// (4096..4863) + wproj transpose (4864..5119). One launch, runs concurrently.
__global__ __launch_bounds__(256) void k_prep(const float* __restrict__ hs,
                                              ushort_t* __restrict__ hsb,
                                              const float* __restrict__ wqkv,
                                              ushort_t* __restrict__ wqkvT,
                                              const float* __restrict__ wproj,
                                              ushort_t* __restrict__ wprojT) {
  __shared__ ushort_t t[64 * 65];
  const int bid = blockIdx.x;
  if (bid < 4096) {  // ---- convert hs fp32 -> bf16, 8 elems/thread
    int i = bid * 256 + threadIdx.x;
    const float4* s4 = (const float4*)hs;
    float4 a = s4[(size_t)i * 2], b = s4[(size_t)i * 2 + 1];
    short8 o;
    o[0] = (short)f2bf(a.x); o[1] = (short)f2bf(a.y);
    o[2] = (short)f2bf(a.z); o[3] = (short)f2bf(a.w);
    o[4] = (short)f2bf(b.x); o[5] = (short)f2bf(b.y);
    o[6] = (short)f2bf(b.z); o[7] = (short)f2bf(b.w);
    *(short8*)(hsb + (size_t)i * 8) = o;
    return;
  }
  // ---- transpose fp32 [1024][C] -> bf16 [C][1024]
  const float* src;
  ushort_t* dst;
  int C, bx, by;
  if (bid < 4864) { int idx = bid - 4096; src = wqkv; dst = wqkvT; C = 3072;
                    bx = idx % 48; by = idx / 48; }
  else            { int idx = bid - 4864; src = wproj; dst = wprojT; C = 1024;
                    bx = idx & 15; by = idx >> 4; }
  const int R = 1024;
  const int x0 = bx * 64, y0 = by * 64;
  const int c = threadIdx.x & 63, r0 = threadIdx.x >> 6;
#pragma unroll
  for (int i = 0; i < 16; ++i) {
    int r = r0 + i * 4;
    t[c * 65 + r] = f2bf(src[(size_t)(y0 + r) * C + x0 + c]);
  }
  __syncthreads();
#pragma unroll
  for (int i = 0; i < 16; ++i) {
    int rr = r0 + i * 4;
    dst[(size_t)(x0 + rr) * R + y0 + c] = t[rr * 65 + c];
  }
}

// ---------------------------------------------------------------- qkv GEMM + RoPE
// NEW this round: ring-4 half-tile pipeline (T3+T4+T5) on the measured-best
// 256x128 tile. K staged as 32 halves of BK=32, ring of 4 LDS slots ->
// prefetch depth 3 halves, counted vmcnt (WAITV(6) steady; 3/0 tail; never a
// drain mid-loop). Per phase: issue 3 gload_lds (half h+3) || 8 ds_read_b128
// || BAR || setprio(1) 16 MFMA setprio(0) || WAITV || BAR.
// LDS 4x(16K A + 8K B) = 96KB -> 1 block/CU; grid 768 = 3 exact rounds.
// 64B-row swizzle: source chunk s^((r>>1)&3), reader (quad^((row>>1)&3))&3
// (only ml<->ml+8 bank-alias -> 2-way, free per m136).
// XCD swizzle, epilogue (RoPE into Q with 0.125*log2(e), K, pi-space V^T)
// identical to the verified r1 kernel.
__global__ __launch_bounds__(512) void k_qkv_gemm_rope(
    const ushort_t* __restrict__ A, const ushort_t* __restrict__ Bt,
    const float* __restrict__ bias, const float* __restrict__ cosb,
    const float* __restrict__ sinb, ushort_t* __restrict__ Qb,
    ushort_t* __restrict__ Kb, ushort_t* __restrict__ Vp) {
  constexpr int K = 1024;
  __shared__ __align__(16) ushort_t As[4][8192];   // ring: A half 256x32
  __shared__ __align__(16) ushort_t Bs[4][4096];   // ring: B half 128x32
  const int tid = threadIdx.x, lane = tid & 63, wave = tid >> 6;
  const int quad = lane >> 4, ml = lane & 15;
  const int wm = wave & 3, wn = wave >> 2;  // 4 waves on M, 2 on N
  const int L = blockIdx.x, xcd = L & 7, j = L >> 3;
  const int by = xcd * 4 + j / 24, bx = j % 24;   // XCD-local A reuse
  const int m0 = by * 256, n0 = bx * 128;
  f32x4 acc[4][4] = {};

  // staging: per half, A 1024 chunks (2/thread) + B 512 chunks (1/thread)
  const ushort_t* ag[2];
  ushort_t* al[2];
  const ushort_t* bg;
  ushort_t* bl;
#pragma unroll
  for (int i = 0; i < 2; ++i) {
    int cch = i * 512 + tid;
    int r = cch >> 2, s = cch & 3, gs = s ^ ((r >> 1) & 3);
    ag[i] = A + (size_t)(m0 + r) * K + gs * 8;
    al[i] = &As[0][0] + cch * 8;
  }
  {
    int r = tid >> 2, s = tid & 3, gs = s ^ ((r >> 1) & 3);
    bg = Bt + (size_t)(n0 + r) * K + gs * 8;
    bl = &Bs[0][0] + tid * 8;
  }

  // reader offsets (per-thread constants, ushort units within a slot)
  int afo[4], bfo[4];
#pragma unroll
  for (int mb = 0; mb < 4; ++mb) {
    int row = wm * 64 + mb * 16 + ml;
    afo[mb] = row * 32 + ((quad ^ ((row >> 1) & 3)) & 3) * 8;
  }
#pragma unroll
  for (int nb = 0; nb < 4; ++nb) {
    int row = wn * 64 + nb * 16 + ml;
    bfo[nb] = row * 32 + ((quad ^ ((row >> 1) & 3)) & 3) * 8;
  }

  // prologue: halves 0,1,2 -> slots 0,1,2 (FIFO per wave: 3 loads per half)
#pragma unroll
  for (int h = 0; h < 3; ++h) {
    load_lds16(ag[0], al[0] + h * 8192); ag[0] += 32;
    load_lds16(ag[1], al[1] + h * 8192); ag[1] += 32;
    load_lds16(bg, bl + h * 4096); bg += 32;
  }
  WAITV(6);  // own half 0 retired (halves 1,2 in flight)
  BAR(); SCHEDB();

  // Per phase h: BUF=h%4, NBUF=(h+3)%4. Hazards: slot NBUF last read in
  // phase h-1 (reads complete before its end-BAR); WAITV(6) retires own
  // half h+1 before the end-BAR -> resident for phase h+1's ds_reads.
#define HSTEP(BUF, NBUF, ISS, WN)                                             \
  {                                                                           \
    if (ISS) {                                                                \
      load_lds16(ag[0], al[0] + (NBUF) * 8192); ag[0] += 32;                  \
      load_lds16(ag[1], al[1] + (NBUF) * 8192); ag[1] += 32;                  \
      load_lds16(bg, bl + (NBUF) * 4096); bg += 32;                           \
    }                                                                         \
    short8 af[4], bfr[4];                                                     \
    _Pragma("unroll") for (int mb = 0; mb < 4; ++mb)                          \
        af[mb] = *(const short8*)(&As[0][0] + (BUF) * 8192 + afo[mb]);        \
    _Pragma("unroll") for (int nb = 0; nb < 4; ++nb)                          \
        bfr[nb] = *(const short8*)(&Bs[0][0] + (BUF) * 4096 + bfo[nb]);       \
    BAR(); SCHEDB();                                                          \
    __builtin_amdgcn_s_setprio(1);                                            \
    _Pragma("unroll") for (int mb = 0; mb < 4; ++mb)                          \
      _Pragma("unroll") for (int nb = 0; nb < 4; ++nb)                        \
          acc[mb][nb] = MFMA16(af[mb], bfr[nb], acc[mb][nb]);                 \
    __builtin_amdgcn_s_setprio(0);                                            \
    WAITV(WN);                                                                \
    BAR(); SCHEDB();                                                          \
  }

#pragma unroll 1
  for (int t = 0; t < 7; ++t) {  // phases 0..27 (issue halves 3..30)
    HSTEP(0, 3, 1, 6)
    HSTEP(1, 0, 1, 6)
    HSTEP(2, 1, 1, 6)
    HSTEP(3, 2, 1, 6)
  }
  HSTEP(0, 3, 1, 6)  // phase 28: issue half 31
  HSTEP(1, 0, 0, 3)  // phase 29: halves 30,31 in flight -> retire 30
  HSTEP(2, 0, 0, 0)  // phase 30: retire 31
  HSTEP(3, 0, 0, 0)  // phase 31
#undef HSTEP

  // epilogue (identical to verified r1)
  const int ncol0 = n0 + wn * 64;
  const int sec = ncol0 >> 10;  // 0=q 1=k 2=v
  const int h = (ncol0 & 1023) >> 6;
  if (sec < 2) {
    ushort_t* dst = (sec == 0) ? Qb : Kb;
    const float qs = (sec == 0) ? 0.18033688011112042f : 1.0f;  // log2(e)/8 into Q
#pragma unroll
    for (int mb = 0; mb < 4; ++mb) {
#pragma unroll
      for (int rg = 0; rg < 4; ++rg) {
        const int m = m0 + wm * 64 + mb * 16 + quad * 4 + rg;
        const int b = m >> 10, l = m & 1023;
        const size_t ob = ((size_t)(b * 16 + h) * 1024 + l) * 64;
#pragma unroll
        for (int nb = 0; nb < 2; ++nb) {
          const int d = nb * 16 + ml;
          float x1 = acc[mb][nb][rg] + bias[ncol0 + d];
          float x2 = acc[mb][nb + 2][rg] + bias[ncol0 + d + 32];
          float cv = cosb[(size_t)m * 64 + d] * qs;
          float sv = sinb[(size_t)m * 64 + d] * qs;
          dst[ob + d] = f2bf(x1 * cv - x2 * sv);
          dst[ob + d + 32] = f2bf(x2 * cv + x1 * sv);
        }
      }
    }
  } else {
    // V^T pi-space: addr = [bh][d][lB + 16*quad + 4*rg + mb], mb packs into b64
    const int mrow = m0 + wm * 64;
    const int b = mrow >> 10, lB = mrow & 1023;
    ushort_t* vb = Vp + ((size_t)(b * 16 + h)) * 65536 + lB;
#pragma unroll
    for (int rg = 0; rg < 4; ++rg) {
#pragma unroll
      for (int nb = 0; nb < 4; ++nb) {
        const int d = nb * 16 + ml;
        const float bs = bias[ncol0 + d];
        uint2 w;
        w.x = pack_bf2(acc[0][nb][rg] + bs, acc[1][nb][rg] + bs);
        w.y = pack_bf2(acc[2][nb][rg] + bs, acc[3][nb][rg] + bs);
        *(uint2*)(vb + (size_t)d * 1024 + 16 * quad + 4 * rg) = w;
      }
    }
  }
}

// ---------------------------------------------------------------- flash attention
// (r9 version: r2fix schedule with collapsed addressing; pass-verified r9)
__global__ __launch_bounds__(512, 4) void k_attn(const ushort_t* __restrict__ Qb,
                                                 const ushort_t* __restrict__ Kb,
                                                 const ushort_t* __restrict__ Vp,
                                                 ushort_t* __restrict__ Ob) {
  __shared__ __align__(16) ushort_t S[32768];  // 64KB unified
  const int tid = threadIdx.x, lane = tid & 63, wave = tid >> 6;
  const int quad = lane >> 4, ml = lane & 15;
  const int bh = blockIdx.x & 127, qt = blockIdx.x >> 7;  // 512 blocks, qt 0..3
  const int q0 = qt * 256;
  const size_t base = (size_t)bh * 65536;

#pragma unroll
  for (int i = 0; i < 4; ++i) {  // stage Q 256x64 once (32KB, 2048 chunks)
    int cch = i * 512 + tid;
    int r = cch >> 3, s = cch & 7, gs = s ^ (r & 7);
    load_lds16(Qb + base + (size_t)(q0 + r) * 64 + gs * 8, S + cch * 8);
  }

  // ---- staging pointers: 512 threads, 512 chunks/tile -> 1 chunk per thread
  const ushort_t* kg;
  const ushort_t* vg;
  ushort_t *kl, *vl;
  {
    int r = tid >> 3, gs = (tid & 7) ^ (r & 7);
    kg = Kb + base + (size_t)r * 64 + gs * 8;
    kl = S + 16384 + tid * 8;
    vg = Vp + base + (size_t)r * 1024 + gs * 8;
    vl = S + 24576 + tid * 8;
  }
  // prologue: K0/V0 into buf 0 (issued with Q; one drain for all)
  load_lds16(kg, kl); kg += 4096;  // next 64 key rows
  load_lds16(vg, vl); vg += 64;    // next 64 pi-cols
  __syncthreads();  // Q + K0 + V0 resident

  // ---- collapsed swizzle offsets (ushort units)
  const int gsA = quad ^ (ml & 7);            // ks=0 group
  const int gsB = (4 + quad) ^ (ml & 7);      // ks=1 group
  const int h0 = (ml >> 1) ^ (quad * 4);      // P-write group seed

  short8 qf[2][2];  // wave w reads only rows [32w,32w+32) == its P region
#pragma unroll
  for (int mb = 0; mb < 2; ++mb) {
    int rowoff = wave * 2048 + mb * 1024 + ml * 64;
    qf[mb][0] = *(const short8*)(S + rowoff + gsA * 8);
    qf[mb][1] = *(const short8*)(S + rowoff + gsB * 8);
  }
  __syncthreads();  // all qf reads done before P aliases Q region

  // ---- the 5 hoisted LDS addresses (all further indexing = immediates)
  const ushort_t* kA = S + 16384 + ml * 64 + gsA * 8;  // K ks=0 (V = +8192)
  const ushort_t* kB = S + 16384 + ml * 64 + gsB * 8;  // K ks=1
  const ushort_t* pA = S + wave * 2048 + ml * 64 + gsA * 8;  // P-read ks=0
  const ushort_t* pB = S + wave * 2048 + ml * 64 + gsB * 8;  // P-read ks=1
  ushort_t* pwl = S + wave * 2048 + quad * 256 + (ml & 1) * 4;  // P-write line

  f32x4 Oacc[2][4] = {};
  float lsum[2][4] = {};

  // Per step (CUR = kt&1, compile-time): ONE barrier, full-step latency window.
#define ATTN_STEP(CUR, LAST)                                                  \
  {                                                                           \
    if (!(LAST)) {                                                            \
      load_lds16(kg, kl + ((CUR) ^ 1) * 4096); kg += 4096;                    \
      load_lds16(vg, vl + ((CUR) ^ 1) * 4096); vg += 64;                      \
    }                                                                         \
    f32x4 Sacc[2][4] = {};                                                    \
    __builtin_amdgcn_s_setprio(1);                                            \
    _Pragma("unroll") for (int nb = 0; nb < 4; ++nb) {                        \
      short8 kfa = *(const short8*)(kA + (CUR) * 4096 + nb * 1024);           \
      short8 kfb = *(const short8*)(kB + (CUR) * 4096 + nb * 1024);           \
      Sacc[0][nb] = MFMA16(qf[0][0], kfa, Sacc[0][nb]);                       \
      Sacc[1][nb] = MFMA16(qf[1][0], kfa, Sacc[1][nb]);                       \
      Sacc[0][nb] = MFMA16(qf[0][1], kfb, Sacc[0][nb]);                       \
      Sacc[1][nb] = MFMA16(qf[1][1], kfb, Sacc[1][nb]);                       \
    }                                                                         \
    __builtin_amdgcn_s_setprio(0);                                            \
    _Pragma("unroll") for (int mb = 0; mb < 2; ++mb) {                        \
      _Pragma("unroll") for (int rg = 0; rg < 4; ++rg) {                      \
        float p0 = fast_exp2(Sacc[mb][0][rg]);                                \
        float p1 = fast_exp2(Sacc[mb][1][rg]);                                \
        float p2 = fast_exp2(Sacc[mb][2][rg]);                                \
        float p3 = fast_exp2(Sacc[mb][3][rg]);                                \
        lsum[mb][rg] += (p0 + p1) + (p2 + p3);                                \
        uint2 w;                                                              \
        w.x = pack2(p0, p1);                                                  \
        w.y = pack2(p2, p3);                                                  \
        int g8 = ((h0 ^ rg) & 7) * 8;                                         \
        *(uint2*)(pwl + mb * 1024 + rg * 64 + g8) = w;                        \
      }                                                                       \
    }                                                                         \
    __builtin_amdgcn_s_setprio(1);                                            \
    _Pragma("unroll") for (int ks = 0; ks < 2; ++ks) {                        \
      const ushort_t* pk = ks ? pB : pA;                                      \
      const ushort_t* vk = (ks ? kB : kA) + 8192 + (CUR) * 4096;              \
      short8 pf0 = *(const short8*)(pk);                                      \
      short8 pf1 = *(const short8*)(pk + 1024);                               \
      _Pragma("unroll") for (int nb = 0; nb < 4; ++nb) {                      \
        short8 vf = *(const short8*)(vk + nb * 1024);                         \
        Oacc[0][nb] = MFMA16(pf0, vf, Oacc[0][nb]);                           \
        Oacc[1][nb] = MFMA16(pf1, vf, Oacc[1][nb]);                           \
      }                                                                       \
    }                                                                         \
    __builtin_amdgcn_s_setprio(0);                                            \
    __syncthreads();                                                          \
  }

#pragma unroll 1
  for (int kt2 = 0; kt2 < 8; ++kt2) {
    ATTN_STEP(0, false)
    ATTN_STEP(1, kt2 == 7)
  }
#undef ATTN_STEP

  // epilogue: reduce lsum across the 16 lanes of each quad, normalize, store
  const int b = bh >> 4, h = bh & 15;
#pragma unroll
  for (int mb = 0; mb < 2; ++mb) {
#pragma unroll
    for (int rg = 0; rg < 4; ++rg) {
      float l = lsum[mb][rg];
      l += __shfl_xor(l, 1);
      l += __shfl_xor(l, 2);
      l += __shfl_xor(l, 4);
      l += __shfl_xor(l, 8);
      float inv = 1.f / l;
      int q = q0 + wave * 32 + mb * 16 + quad * 4 + rg;
      size_t ob = ((size_t)(b * 1024 + q)) * 1024 + h * 64;
#pragma unroll
      for (int nb = 0; nb < 4; ++nb)
        Ob[ob + nb * 16 + ml] = f2bf(Oacc[mb][nb][rg] * inv);
    }
  }
}

// ---------------------------------------------------------------- proj GEMM
// (round-7 config: 128x128, BK=128)
// A: attn bf16 [8192][1024], Bt: wproj^T bf16 [1024][1024].
// 1D grid 512, XCD-swizzled: xcd=L&7, j=L>>3, y=xcd*8+j/8, x=j%8.
__global__ __launch_bounds__(256) void k_proj_gemm(const ushort_t* __restrict__ A,
                                                   const ushort_t* __restrict__ Bt,
                                                   const float* __restrict__ bias,
                                                   float* __restrict__ out) {
  constexpr int K = 1024;
  __shared__ __align__(16) ushort_t As[128 * 128];
  __shared__ __align__(16) ushort_t Bs[128 * 128];
  const int tid = threadIdx.x, lane = tid & 63, wave = tid >> 6;
  const int quad = lane >> 4, ml = lane & 15;
  const int wm = wave & 1, wn = wave >> 1;
  const int L = blockIdx.x, xcd = L & 7, j = L >> 3;
  const int by = xcd * 8 + (j >> 3), bx = j & 7;
  const int m0 = by * 128, n0 = bx * 128;
  f32x4 acc[4][4] = {};

  for (int kt = 0; kt < K / 128; ++kt) {
    __syncthreads();
    {
      const int kk0 = kt * 128;
#pragma unroll
      for (int i = 0; i < 8; ++i) {  // 128x128 tiles: 2048 chunks of 16B each
        int cch = i * 256 + tid;
        int r = cch >> 4, s = cch & 15, gs = s ^ (r & 15);
        load_lds16(A + (size_t)(m0 + r) * K + kk0 + gs * 8, As + cch * 8);
        load_lds16(Bt + (size_t)(n0 + r) * K + kk0 + gs * 8, Bs + cch * 8);
      }
    }
    __syncthreads();
#pragma unroll
    for (int ks = 0; ks < 4; ++ks) {
      short8 af[4], bfr[4];
#pragma unroll
      for (int mb = 0; mb < 4; ++mb) {
        int row = wm * 64 + mb * 16 + ml;
        int gs = (ks * 4 + quad) ^ (row & 15);
        af[mb] = *(const short8*)(As + row * 128 + gs * 8);
      }
#pragma unroll
      for (int nb = 0; nb < 4; ++nb) {
        int row = wn * 64 + nb * 16 + ml;
        int gs = (ks * 4 + quad) ^ (row & 15);
        bfr[nb] = *(const short8*)(Bs + row * 128 + gs * 8);
      }
#pragma unroll
      for (int mb = 0; mb < 4; ++mb)
#pragma unroll
        for (int nb = 0; nb < 4; ++nb)
          acc[mb][nb] = MFMA16(af[mb], bfr[nb], acc[mb][nb]);
    }
  }
#pragma unroll
  for (int mb = 0; mb < 4; ++mb) {
#pragma unroll
    for (int rg = 0; rg < 4; ++rg) {
      const int m = m0 + wm * 64 + mb * 16 + quad * 4 + rg;
#pragma unroll
      for (int nb = 0; nb < 4; ++nb) {
        const int n = n0 + wn * 64 + nb * 16 + ml;
        out[(size_t)m * 1024 + n] = acc[mb][nb][rg] + bias[n];
      }
    }
  }
}

// ---------------------------------------------------------------- launch
extern "C" void kernel_launch(void* const* d_in, const int* in_sizes, int n_in,
                              void* d_out, int out_size, void* d_ws, size_t ws_size,
                              hipStream_t stream) {
  const float* hs = (const float*)d_in[0];
  const float* cosb = (const float*)d_in[1];
  const float* sinb = (const float*)d_in[2];
  const float* wqkv = (const float*)d_in[3];
  const float* bqkv = (const float*)d_in[4];
  const float* wproj = (const float*)d_in[5];
  const float* bproj = (const float*)d_in[6];
  float* out = (float*)d_out;

  char* ws = (char*)d_ws;
  ushort_t* hsb = (ushort_t*)(ws);
  ushort_t* wqkvT = (ushort_t*)(ws + (16u << 20));
  ushort_t* wprojT = (ushort_t*)(ws + (22u << 20));
  ushort_t* Qb = (ushort_t*)(ws + (24u << 20));
  ushort_t* Kb = (ushort_t*)(ws + (40u << 20));
  ushort_t* Vp = (ushort_t*)(ws + (56u << 20));
  ushort_t* attnb = hsb;  // hs consumed by qkv GEMM before attention writes

  k_prep<<<5120, 256, 0, stream>>>(hs, hsb, wqkv, wqkvT, wproj, wprojT);
  k_qkv_gemm_rope<<<768, 512, 0, stream>>>(hsb, wqkvT, bqkv, cosb, sinb,
                                           Qb, Kb, Vp);
  k_attn<<<512, 512, 0, stream>>>(Qb, Kb, Vp, attnb);
  k_proj_gemm<<<512, 256, 0, stream>>>(attnb, wprojT, bproj, out);
}

// Round 12
// 243.265 us; speedup vs baseline: 1.0547x; 1.0547x over previous
//
#include <hip/hip_runtime.h>

typedef unsigned short ushort_t;
typedef __attribute__((ext_vector_type(8))) short short8;
typedef __attribute__((ext_vector_type(4))) float f32x4;

#define AS1 __attribute__((address_space(1)))
#define AS3 __attribute__((address_space(3)))

__device__ __forceinline__ ushort_t f2bf(float f) {
  unsigned int u = __builtin_bit_cast(unsigned int, f);
  u += 0x7fffu + ((u >> 16) & 1u);            // round-to-nearest-even
  return (ushort_t)(u >> 16);
}

// pack two floats to bf16x2 (round-half-up fallback; HW cvt_pk when available)
__device__ __forceinline__ unsigned int pack_bf2(float a, float b) {
  unsigned int ua = __builtin_bit_cast(unsigned int, a) + 0x8000u;
  unsigned int ub = __builtin_bit_cast(unsigned int, b) + 0x8000u;
  return (ua >> 16) | (ub & 0xffff0000u);
}

#if defined(__has_builtin)
#if __has_builtin(__builtin_amdgcn_cvt_pk_bf16_f32)
#define HAVE_CVT_PK_BF16 1
#endif
#if __has_builtin(__builtin_amdgcn_exp2f)
#define HAVE_EXP2 1
#endif
#endif

__device__ __forceinline__ unsigned int pack2(float a, float b) {
#ifdef HAVE_CVT_PK_BF16
  typedef __attribute__((ext_vector_type(2))) __bf16 bf2_t;
  bf2_t r = __builtin_amdgcn_cvt_pk_bf16_f32(a, b);
  return __builtin_bit_cast(unsigned int, r);
#else
  return pack_bf2(a, b);
#endif
}

__device__ __forceinline__ float fast_exp2(float x) {
#ifdef HAVE_EXP2
  return __builtin_amdgcn_exp2f(x);
#else
  return exp2f(x);
#endif
}

__device__ __forceinline__ void load_lds16(const ushort_t* g, ushort_t* l) {
  __builtin_amdgcn_global_load_lds((AS1 void*)g, (AS3 void*)l, 16, 0, 0);
}

#define MFMA16(a, b, c) __builtin_amdgcn_mfma_f32_16x16x32_bf16((a), (b), (c), 0, 0, 0)

// ---------------- fused prep: hs convert (blocks 0..4095) + wqkv transpose
// (4096..4863) + wproj transpose (4864..5119). One launch, runs concurrently.
__global__ __launch_bounds__(256) void k_prep(const float* __restrict__ hs,
                                              ushort_t* __restrict__ hsb,
                                              const float* __restrict__ wqkv,
                                              ushort_t* __restrict__ wqkvT,
                                              const float* __restrict__ wproj,
                                              ushort_t* __restrict__ wprojT) {
  __shared__ ushort_t t[64 * 65];
  const int bid = blockIdx.x;
  if (bid < 4096) {  // ---- convert hs fp32 -> bf16, 8 elems/thread
    int i = bid * 256 + threadIdx.x;
    const float4* s4 = (const float4*)hs;
    float4 a = s4[(size_t)i * 2], b = s4[(size_t)i * 2 + 1];
    short8 o;
    o[0] = (short)f2bf(a.x); o[1] = (short)f2bf(a.y);
    o[2] = (short)f2bf(a.z); o[3] = (short)f2bf(a.w);
    o[4] = (short)f2bf(b.x); o[5] = (short)f2bf(b.y);
    o[6] = (short)f2bf(b.z); o[7] = (short)f2bf(b.w);
    *(short8*)(hsb + (size_t)i * 8) = o;
    return;
  }
  // ---- transpose fp32 [1024][C] -> bf16 [C][1024]
  const float* src;
  ushort_t* dst;
  int C, bx, by;
  if (bid < 4864) { int idx = bid - 4096; src = wqkv; dst = wqkvT; C = 3072;
                    bx = idx % 48; by = idx / 48; }
  else            { int idx = bid - 4864; src = wproj; dst = wprojT; C = 1024;
                    bx = idx & 15; by = idx >> 4; }
  const int R = 1024;
  const int x0 = bx * 64, y0 = by * 64;
  const int c = threadIdx.x & 63, r0 = threadIdx.x >> 6;
#pragma unroll
  for (int i = 0; i < 16; ++i) {
    int r = r0 + i * 4;
    t[c * 65 + r] = f2bf(src[(size_t)(y0 + r) * C + x0 + c]);
  }
  __syncthreads();
#pragma unroll
  for (int i = 0; i < 16; ++i) {
    int rr = r0 + i * 4;
    dst[(size_t)(x0 + rr) * R + y0 + c] = t[rr * 65 + c];
  }
}

// ---------------------------------------------------------------- qkv GEMM + RoPE
// (round-1 measured-best version: ~70.5 us, 732 TF, MfmaUtil ~29%, VGPR 60.
// Explicit pipelines lose the 3-blocks/CU TLP that hides the drain here —
// measured 3x this session: r3 77.4, r5 218.6, r10 88.5 vs this 70.5.)
// A: hs bf16 [8192][1024], Bt: wqkv^T bf16 [3072][1024]
// 256x128 tile, BK=64, 512 threads (8 waves: 4 on M x 2 on N, 64x64 each).
// 1D grid 768, XCD-swizzled: xcd=L&7, j=L>>3, y=xcd*4+j/24, x=j%24.
// Q: RoPE'd AND pre-scaled by 0.125*log2(e). K: RoPE'd [B*H][L][D].
// V: transposed pi-space Vp[bh][d][lB + pi(lt)], pi(lt)=4*(lt&15)+(lt>>4).
__global__ __launch_bounds__(512) void k_qkv_gemm_rope(
    const ushort_t* __restrict__ A, const ushort_t* __restrict__ Bt,
    const float* __restrict__ bias, const float* __restrict__ cosb,
    const float* __restrict__ sinb, ushort_t* __restrict__ Qb,
    ushort_t* __restrict__ Kb, ushort_t* __restrict__ Vp) {
  constexpr int K = 1024;
  __shared__ __align__(16) ushort_t As[256 * 64];
  __shared__ __align__(16) ushort_t Bs[128 * 64];
  const int tid = threadIdx.x, lane = tid & 63, wave = tid >> 6;
  const int quad = lane >> 4, ml = lane & 15;
  const int wm = wave & 3, wn = wave >> 2;  // 4 waves on M, 2 on N
  const int L = blockIdx.x, xcd = L & 7, j = L >> 3;
  const int by = xcd * 4 + j / 24, bx = j % 24;   // XCD-local A reuse
  const int m0 = by * 256, n0 = bx * 128;
  f32x4 acc[4][4] = {};

  for (int kt = 0; kt < K / 64; ++kt) {
    __syncthreads();
    {
      const int kk0 = kt * 64;
#pragma unroll
      for (int i = 0; i < 4; ++i) {  // A-tile 256x64
        int cch = i * 512 + tid;
        int r = cch >> 3, s = cch & 7, gs = s ^ (r & 7);
        load_lds16(A + (size_t)(m0 + r) * K + kk0 + gs * 8, As + cch * 8);
      }
#pragma unroll
      for (int i = 0; i < 2; ++i) {  // B-tile 128x64
        int cch = i * 512 + tid;
        int r = cch >> 3, s = cch & 7, gs = s ^ (r & 7);
        load_lds16(Bt + (size_t)(n0 + r) * K + kk0 + gs * 8, Bs + cch * 8);
      }
    }
    __syncthreads();
#pragma unroll
    for (int ks = 0; ks < 2; ++ks) {
      short8 af[4], bfr[4];
#pragma unroll
      for (int mb = 0; mb < 4; ++mb) {
        int row = wm * 64 + mb * 16 + ml;
        int gs = (ks * 4 + quad) ^ (row & 7);
        af[mb] = *(const short8*)(As + row * 64 + gs * 8);
      }
#pragma unroll
      for (int nb = 0; nb < 4; ++nb) {
        int row = wn * 64 + nb * 16 + ml;
        int gs = (ks * 4 + quad) ^ (row & 7);
        bfr[nb] = *(const short8*)(Bs + row * 64 + gs * 8);
      }
#pragma unroll
      for (int mb = 0; mb < 4; ++mb)
#pragma unroll
        for (int nb = 0; nb < 4; ++nb)
          acc[mb][nb] = MFMA16(af[mb], bfr[nb], acc[mb][nb]);
    }
  }

  // epilogue
  const int ncol0 = n0 + wn * 64;
  const int sec = ncol0 >> 10;  // 0=q 1=k 2=v
  const int h = (ncol0 & 1023) >> 6;
  if (sec < 2) {
    ushort_t* dst = (sec == 0) ? Qb : Kb;
    const float qs = (sec == 0) ? 0.18033688011112042f : 1.0f;  // log2(e)/8 into Q
#pragma unroll
    for (int mb = 0; mb < 4; ++mb) {
#pragma unroll
      for (int rg = 0; rg < 4; ++rg) {
        const int m = m0 + wm * 64 + mb * 16 + quad * 4 + rg;
        const int b = m >> 10, l = m & 1023;
        const size_t ob = ((size_t)(b * 16 + h) * 1024 + l) * 64;
#pragma unroll
        for (int nb = 0; nb < 2; ++nb) {
          const int d = nb * 16 + ml;
          float x1 = acc[mb][nb][rg] + bias[ncol0 + d];
          float x2 = acc[mb][nb + 2][rg] + bias[ncol0 + d + 32];
          float cv = cosb[(size_t)m * 64 + d] * qs;
          float sv = sinb[(size_t)m * 64 + d] * qs;
          dst[ob + d] = f2bf(x1 * cv - x2 * sv);
          dst[ob + d + 32] = f2bf(x2 * cv + x1 * sv);
        }
      }
    }
  } else {
    // V^T pi-space: addr = [bh][d][lB + 16*quad + 4*rg + mb], mb packs into b64
    const int mrow = m0 + wm * 64;
    const int b = mrow >> 10, lB = mrow & 1023;
    ushort_t* vb = Vp + ((size_t)(b * 16 + h)) * 65536 + lB;
#pragma unroll
    for (int rg = 0; rg < 4; ++rg) {
#pragma unroll
      for (int nb = 0; nb < 4; ++nb) {
        const int d = nb * 16 + ml;
        const float bs = bias[ncol0 + d];
        uint2 w;
        w.x = pack_bf2(acc[0][nb][rg] + bs, acc[1][nb][rg] + bs);
        w.y = pack_bf2(acc[2][nb][rg] + bs, acc[3][nb][rg] + bs);
        *(uint2*)(vb + (size_t)d * 1024 + 16 * quad + 4 * rg) = w;
      }
    }
  }
}

// ---------------------------------------------------------------- flash attention
// (r9 version: r2fix schedule with collapsed addressing; pass-verified r9)
// 512 threads (8 waves x 32 q = 256 q/block); K and V double-buffered, ONE
// barrier per kt-step; P wave-private, aliases Q region. LDS 64KB unified:
// S[0..16K)=Q/P, [16K..24K)=K dbuf, [24K..32K)=V dbuf (ushorts). 2 blocks/CU.
__global__ __launch_bounds__(512, 4) void k_attn(const ushort_t* __restrict__ Qb,
                                                 const ushort_t* __restrict__ Kb,
                                                 const ushort_t* __restrict__ Vp,
                                                 ushort_t* __restrict__ Ob) {
  __shared__ __align__(16) ushort_t S[32768];  // 64KB unified
  const int tid = threadIdx.x, lane = tid & 63, wave = tid >> 6;
  const int quad = lane >> 4, ml = lane & 15;
  const int bh = blockIdx.x & 127, qt = blockIdx.x >> 7;  // 512 blocks, qt 0..3
  const int q0 = qt * 256;
  const size_t base = (size_t)bh * 65536;

#pragma unroll
  for (int i = 0; i < 4; ++i) {  // stage Q 256x64 once (32KB, 2048 chunks)
    int cch = i * 512 + tid;
    int r = cch >> 3, s = cch & 7, gs = s ^ (r & 7);
    load_lds16(Qb + base + (size_t)(q0 + r) * 64 + gs * 8, S + cch * 8);
  }

  // ---- staging pointers: 512 threads, 512 chunks/tile -> 1 chunk per thread
  const ushort_t* kg;
  const ushort_t* vg;
  ushort_t *kl, *vl;
  {
    int r = tid >> 3, gs = (tid & 7) ^ (r & 7);
    kg = Kb + base + (size_t)r * 64 + gs * 8;
    kl = S + 16384 + tid * 8;
    vg = Vp + base + (size_t)r * 1024 + gs * 8;
    vl = S + 24576 + tid * 8;
  }
  // prologue: K0/V0 into buf 0 (issued with Q; one drain for all)
  load_lds16(kg, kl); kg += 4096;  // next 64 key rows
  load_lds16(vg, vl); vg += 64;    // next 64 pi-cols
  __syncthreads();  // Q + K0 + V0 resident

  // ---- collapsed swizzle offsets (ushort units)
  const int gsA = quad ^ (ml & 7);            // ks=0 group
  const int gsB = (4 + quad) ^ (ml & 7);      // ks=1 group
  const int h0 = (ml >> 1) ^ (quad * 4);      // P-write group seed

  short8 qf[2][2];  // wave w reads only rows [32w,32w+32) == its P region
#pragma unroll
  for (int mb = 0; mb < 2; ++mb) {
    int rowoff = wave * 2048 + mb * 1024 + ml * 64;
    qf[mb][0] = *(const short8*)(S + rowoff + gsA * 8);
    qf[mb][1] = *(const short8*)(S + rowoff + gsB * 8);
  }
  __syncthreads();  // all qf reads done before P aliases Q region

  // ---- the 5 hoisted LDS addresses (all further indexing = immediates)
  const ushort_t* kA = S + 16384 + ml * 64 + gsA * 8;  // K ks=0 (V = +8192)
  const ushort_t* kB = S + 16384 + ml * 64 + gsB * 8;  // K ks=1
  const ushort_t* pA = S + wave * 2048 + ml * 64 + gsA * 8;  // P-read ks=0
  const ushort_t* pB = S + wave * 2048 + ml * 64 + gsB * 8;  // P-read ks=1
  ushort_t* pwl = S + wave * 2048 + quad * 256 + (ml & 1) * 4;  // P-write line

  f32x4 Oacc[2][4] = {};
  float lsum[2][4] = {};

  // Per step (CUR = kt&1, compile-time): ONE barrier, full-step latency window.
#define ATTN_STEP(CUR, LAST)                                                  \
  {                                                                           \
    if (!(LAST)) {                                                            \
      load_lds16(kg, kl + ((CUR) ^ 1) * 4096); kg += 4096;                    \
      load_lds16(vg, vl + ((CUR) ^ 1) * 4096); vg += 64;                      \
    }                                                                         \
    f32x4 Sacc[2][4] = {};                                                    \
    __builtin_amdgcn_s_setprio(1);                                            \
    _Pragma("unroll") for (int nb = 0; nb < 4; ++nb) {                        \
      short8 kfa = *(const short8*)(kA + (CUR) * 4096 + nb * 1024);           \
      short8 kfb = *(const short8*)(kB + (CUR) * 4096 + nb * 1024);           \
      Sacc[0][nb] = MFMA16(qf[0][0], kfa, Sacc[0][nb]);                       \
      Sacc[1][nb] = MFMA16(qf[1][0], kfa, Sacc[1][nb]);                       \
      Sacc[0][nb] = MFMA16(qf[0][1], kfb, Sacc[0][nb]);                       \
      Sacc[1][nb] = MFMA16(qf[1][1], kfb, Sacc[1][nb]);                       \
    }                                                                         \
    __builtin_amdgcn_s_setprio(0);                                            \
    _Pragma("unroll") for (int mb = 0; mb < 2; ++mb) {                        \
      _Pragma("unroll") for (int rg = 0; rg < 4; ++rg) {                      \
        float p0 = fast_exp2(Sacc[mb][0][rg]);                                \
        float p1 = fast_exp2(Sacc[mb][1][rg]);                                \
        float p2 = fast_exp2(Sacc[mb][2][rg]);                                \
        float p3 = fast_exp2(Sacc[mb][3][rg]);                                \
        lsum[mb][rg] += (p0 + p1) + (p2 + p3);                                \
        uint2 w;                                                              \
        w.x = pack2(p0, p1);                                                  \
        w.y = pack2(p2, p3);                                                  \
        int g8 = ((h0 ^ rg) & 7) * 8;                                         \
        *(uint2*)(pwl + mb * 1024 + rg * 64 + g8) = w;                        \
      }                                                                       \
    }                                                                         \
    __builtin_amdgcn_s_setprio(1);                                            \
    _Pragma("unroll") for (int ks = 0; ks < 2; ++ks) {                        \
      const ushort_t* pk = ks ? pB : pA;                                      \
      const ushort_t* vk = (ks ? kB : kA) + 8192 + (CUR) * 4096;              \
      short8 pf0 = *(const short8*)(pk);                                      \
      short8 pf1 = *(const short8*)(pk + 1024);                               \
      _Pragma("unroll") for (int nb = 0; nb < 4; ++nb) {                      \
        short8 vf = *(const short8*)(vk + nb * 1024);                         \
        Oacc[0][nb] = MFMA16(pf0, vf, Oacc[0][nb]);                           \
        Oacc[1][nb] = MFMA16(pf1, vf, Oacc[1][nb]);                           \
      }                                                                       \
    }                                                                         \
    __builtin_amdgcn_s_setprio(0);                                            \
    __syncthreads();                                                          \
  }

#pragma unroll 1
  for (int kt2 = 0; kt2 < 8; ++kt2) {
    ATTN_STEP(0, false)
    ATTN_STEP(1, kt2 == 7)
  }
#undef ATTN_STEP

  // epilogue: reduce lsum across the 16 lanes of each quad, normalize, store
  const int b = bh >> 4, h = bh & 15;
#pragma unroll
  for (int mb = 0; mb < 2; ++mb) {
#pragma unroll
    for (int rg = 0; rg < 4; ++rg) {
      float l = lsum[mb][rg];
      l += __shfl_xor(l, 1);
      l += __shfl_xor(l, 2);
      l += __shfl_xor(l, 4);
      l += __shfl_xor(l, 8);
      float inv = 1.f / l;
      int q = q0 + wave * 32 + mb * 16 + quad * 4 + rg;
      size_t ob = ((size_t)(b * 1024 + q)) * 1024 + h * 64;
#pragma unroll
      for (int nb = 0; nb < 4; ++nb)
        Ob[ob + nb * 16 + ml] = f2bf(Oacc[mb][nb][rg] * inv);
    }
  }
}

// ---------------------------------------------------------------- proj GEMM
// (round-7 config: 128x128, BK=128; r8's higher-occupancy retile was neutral)
// A: attn bf16 [8192][1024], Bt: wproj^T bf16 [1024][1024].
// 1D grid 512, XCD-swizzled: xcd=L&7, j=L>>3, y=xcd*8+j/8, x=j%8.
__global__ __launch_bounds__(256) void k_proj_gemm(const ushort_t* __restrict__ A,
                                                   const ushort_t* __restrict__ Bt,
                                                   const float* __restrict__ bias,
                                                   float* __restrict__ out) {
  constexpr int K = 1024;
  __shared__ __align__(16) ushort_t As[128 * 128];
  __shared__ __align__(16) ushort_t Bs[128 * 128];
  const int tid = threadIdx.x, lane = tid & 63, wave = tid >> 6;
  const int quad = lane >> 4, ml = lane & 15;
  const int wm = wave & 1, wn = wave >> 1;
  const int L = blockIdx.x, xcd = L & 7, j = L >> 3;
  const int by = xcd * 8 + (j >> 3), bx = j & 7;
  const int m0 = by * 128, n0 = bx * 128;
  f32x4 acc[4][4] = {};

  for (int kt = 0; kt < K / 128; ++kt) {
    __syncthreads();
    {
      const int kk0 = kt * 128;
#pragma unroll
      for (int i = 0; i < 8; ++i) {  // 128x128 tiles: 2048 chunks of 16B each
        int cch = i * 256 + tid;
        int r = cch >> 4, s = cch & 15, gs = s ^ (r & 15);
        load_lds16(A + (size_t)(m0 + r) * K + kk0 + gs * 8, As + cch * 8);
        load_lds16(Bt + (size_t)(n0 + r) * K + kk0 + gs * 8, Bs + cch * 8);
      }
    }
    __syncthreads();
#pragma unroll
    for (int ks = 0; ks < 4; ++ks) {
      short8 af[4], bfr[4];
#pragma unroll
      for (int mb = 0; mb < 4; ++mb) {
        int row = wm * 64 + mb * 16 + ml;
        int gs = (ks * 4 + quad) ^ (row & 15);
        af[mb] = *(const short8*)(As + row * 128 + gs * 8);
      }
#pragma unroll
      for (int nb = 0; nb < 4; ++nb) {
        int row = wn * 64 + nb * 16 + ml;
        int gs = (ks * 4 + quad) ^ (row & 15);
        bfr[nb] = *(const short8*)(Bs + row * 128 + gs * 8);
      }
#pragma unroll
      for (int mb = 0; mb < 4; ++mb)
#pragma unroll
        for (int nb = 0; nb < 4; ++nb)
          acc[mb][nb] = MFMA16(af[mb], bfr[nb], acc[mb][nb]);
    }
  }
#pragma unroll
  for (int mb = 0; mb < 4; ++mb) {
#pragma unroll
    for (int rg = 0; rg < 4; ++rg) {
      const int m = m0 + wm * 64 + mb * 16 + quad * 4 + rg;
#pragma unroll
      for (int nb = 0; nb < 4; ++nb) {
        const int n = n0 + wn * 64 + nb * 16 + ml;
        out[(size_t)m * 1024 + n] = acc[mb][nb][rg] + bias[n];
      }
    }
  }
}

// ---------------------------------------------------------------- launch
extern "C" void kernel_launch(void* const* d_in, const int* in_sizes, int n_in,
                              void* d_out, int out_size, void* d_ws, size_t ws_size,
                              hipStream_t stream) {
  const float* hs = (const float*)d_in[0];
  const float* cosb = (const float*)d_in[1];
  const float* sinb = (const float*)d_in[2];
  const float* wqkv = (const float*)d_in[3];
  const float* bqkv = (const float*)d_in[4];
  const float* wproj = (const float*)d_in[5];
  const float* bproj = (const float*)d_in[6];
  float* out = (float*)d_out;

  char* ws = (char*)d_ws;
  ushort_t* hsb = (ushort_t*)(ws);
  ushort_t* wqkvT = (ushort_t*)(ws + (16u << 20));
  ushort_t* wprojT = (ushort_t*)(ws + (22u << 20));
  ushort_t* Qb = (ushort_t*)(ws + (24u << 20));
  ushort_t* Kb = (ushort_t*)(ws + (40u << 20));
  ushort_t* Vp = (ushort_t*)(ws + (56u << 20));
  ushort_t* attnb = hsb;  // hs consumed by qkv GEMM before attention writes

  k_prep<<<5120, 256, 0, stream>>>(hs, hsb, wqkv, wqkvT, wproj, wprojT);
  k_qkv_gemm_rope<<<768, 512, 0, stream>>>(hsb, wqkvT, bqkv, cosb, sinb,
                                           Qb, Kb, Vp);
  k_attn<<<512, 512, 0, stream>>>(Qb, Kb, Vp, attnb);
  k_proj_gemm<<<512, 256, 0, stream>>>(attnb, wprojT, bproj, out);
}

// Round 13
// 234.437 us; speedup vs baseline: 1.0944x; 1.0377x over previous
//
#include <hip/hip_runtime.h>

typedef unsigned short ushort_t;
typedef __attribute__((ext_vector_type(8))) short short8;
typedef __attribute__((ext_vector_type(4))) float f32x4;

#define AS1 __attribute__((address_space(1)))
#define AS3 __attribute__((address_space(3)))

__device__ __forceinline__ ushort_t f2bf(float f) {
  unsigned int u = __builtin_bit_cast(unsigned int, f);
  u += 0x7fffu + ((u >> 16) & 1u);            // round-to-nearest-even
  return (ushort_t)(u >> 16);
}

// pack two floats to bf16x2 (round-half-up fallback; HW cvt_pk when available)
__device__ __forceinline__ unsigned int pack_bf2(float a, float b) {
  unsigned int ua = __builtin_bit_cast(unsigned int, a) + 0x8000u;
  unsigned int ub = __builtin_bit_cast(unsigned int, b) + 0x8000u;
  return (ua >> 16) | (ub & 0xffff0000u);
}

#if defined(__has_builtin)
#if __has_builtin(__builtin_amdgcn_cvt_pk_bf16_f32)
#define HAVE_CVT_PK_BF16 1
#endif
#if __has_builtin(__builtin_amdgcn_exp2f)
#define HAVE_EXP2 1
#endif
#endif

__device__ __forceinline__ unsigned int pack2(float a, float b) {
#ifdef HAVE_CVT_PK_BF16
  typedef __attribute__((ext_vector_type(2))) __bf16 bf2_t;
  bf2_t r = __builtin_amdgcn_cvt_pk_bf16_f32(a, b);
  return __builtin_bit_cast(unsigned int, r);
#else
  return pack_bf2(a, b);
#endif
}

__device__ __forceinline__ float fast_exp2(float x) {
#ifdef HAVE_EXP2
  return __builtin_amdgcn_exp2f(x);
#else
  return exp2f(x);
#endif
}

__device__ __forceinline__ void load_lds16(const ushort_t* g, ushort_t* l) {
  __builtin_amdgcn_global_load_lds((AS1 void*)g, (AS3 void*)l, 16, 0, 0);
}

#define MFMA16(a, b, c) __builtin_amdgcn_mfma_f32_16x16x32_bf16((a), (b), (c), 0, 0, 0)

// ---------------- fused prep: hs convert (blocks 0..4095) + wqkv transpose
// (4096..4863) + wproj transpose (4864..5119). One launch, runs concurrently.
// NEW this round: transpose path vectorized 2x — float2 loads (8B/lane),
// packed uint (2xbf16) stores (4B/lane). LDS pad 66 (not 65): byte offset
// 132*rr + 4*a2 is 4B-aligned for the uint read; read-phase dword index
// 33*rr + a2 spans 32 distinct banks (conflict-free); write phase 2-way (free).
__global__ __launch_bounds__(256) void k_prep(const float* __restrict__ hs,
                                              ushort_t* __restrict__ hsb,
                                              const float* __restrict__ wqkv,
                                              ushort_t* __restrict__ wqkvT,
                                              const float* __restrict__ wproj,
                                              ushort_t* __restrict__ wprojT) {
  __shared__ __align__(16) ushort_t t[64 * 66];
  const int bid = blockIdx.x;
  if (bid < 4096) {  // ---- convert hs fp32 -> bf16, 8 elems/thread
    int i = bid * 256 + threadIdx.x;
    const float4* s4 = (const float4*)hs;
    float4 a = s4[(size_t)i * 2], b = s4[(size_t)i * 2 + 1];
    short8 o;
    o[0] = (short)f2bf(a.x); o[1] = (short)f2bf(a.y);
    o[2] = (short)f2bf(a.z); o[3] = (short)f2bf(a.w);
    o[4] = (short)f2bf(b.x); o[5] = (short)f2bf(b.y);
    o[6] = (short)f2bf(b.z); o[7] = (short)f2bf(b.w);
    *(short8*)(hsb + (size_t)i * 8) = o;
    return;
  }
  // ---- transpose fp32 [1024][C] -> bf16 [C][1024]  (t[a][b] = src[b][a])
  const float* src;
  ushort_t* dst;
  int C, bx, by;
  if (bid < 4864) { int idx = bid - 4096; src = wqkv; dst = wqkvT; C = 3072;
                    bx = idx % 48; by = idx / 48; }
  else            { int idx = bid - 4864; src = wproj; dst = wprojT; C = 1024;
                    bx = idx & 15; by = idx >> 4; }
  const int R = 1024;
  const int x0 = bx * 64, y0 = by * 64;
  const int a2 = threadIdx.x & 31;   // column-pair: x-cols 2*a2, 2*a2+1
  const int r0 = threadIdx.x >> 5;   // 0..7
#pragma unroll
  for (int i = 0; i < 8; ++i) {
    int r = r0 + i * 8;              // source row within tile
    float2 v = *(const float2*)&src[(size_t)(y0 + r) * C + x0 + 2 * a2];
    t[(2 * a2) * 66 + r]     = f2bf(v.x);
    t[(2 * a2 + 1) * 66 + r] = f2bf(v.y);
  }
  __syncthreads();
#pragma unroll
  for (int i = 0; i < 8; ++i) {
    int rr = r0 + i * 8;             // dst row within tile (= src col)
    unsigned int w = *(const unsigned int*)&t[rr * 66 + 2 * a2];
    *(unsigned int*)&dst[(size_t)(x0 + rr) * R + y0 + 2 * a2] = w;
  }
}

// ---------------------------------------------------------------- qkv GEMM + RoPE
// (round-1 measured-best version: ~70.5 us, 732 TF, MfmaUtil ~29%, VGPR 60.
// Explicit pipelines lose the 3-blocks/CU TLP that hides the drain here —
// measured 3x this session: r3 77.4, r5 218.6, r10 88.5 vs this 70.5.)
// A: hs bf16 [8192][1024], Bt: wqkv^T bf16 [3072][1024]
// 256x128 tile, BK=64, 512 threads (8 waves: 4 on M x 2 on N, 64x64 each).
// 1D grid 768, XCD-swizzled: xcd=L&7, j=L>>3, y=xcd*4+j/24, x=j%24.
// Q: RoPE'd AND pre-scaled by 0.125*log2(e). K: RoPE'd [B*H][L][D].
// V: transposed pi-space Vp[bh][d][lB + pi(lt)], pi(lt)=4*(lt&15)+(lt>>4).
__global__ __launch_bounds__(512) void k_qkv_gemm_rope(
    const ushort_t* __restrict__ A, const ushort_t* __restrict__ Bt,
    const float* __restrict__ bias, const float* __restrict__ cosb,
    const float* __restrict__ sinb, ushort_t* __restrict__ Qb,
    ushort_t* __restrict__ Kb, ushort_t* __restrict__ Vp) {
  constexpr int K = 1024;
  __shared__ __align__(16) ushort_t As[256 * 64];
  __shared__ __align__(16) ushort_t Bs[128 * 64];
  const int tid = threadIdx.x, lane = tid & 63, wave = tid >> 6;
  const int quad = lane >> 4, ml = lane & 15;
  const int wm = wave & 3, wn = wave >> 2;  // 4 waves on M, 2 on N
  const int L = blockIdx.x, xcd = L & 7, j = L >> 3;
  const int by = xcd * 4 + j / 24, bx = j % 24;   // XCD-local A reuse
  const int m0 = by * 256, n0 = bx * 128;
  f32x4 acc[4][4] = {};

  for (int kt = 0; kt < K / 64; ++kt) {
    __syncthreads();
    {
      const int kk0 = kt * 64;
#pragma unroll
      for (int i = 0; i < 4; ++i) {  // A-tile 256x64
        int cch = i * 512 + tid;
        int r = cch >> 3, s = cch & 7, gs = s ^ (r & 7);
        load_lds16(A + (size_t)(m0 + r) * K + kk0 + gs * 8, As + cch * 8);
      }
#pragma unroll
      for (int i = 0; i < 2; ++i) {  // B-tile 128x64
        int cch = i * 512 + tid;
        int r = cch >> 3, s = cch & 7, gs = s ^ (r & 7);
        load_lds16(Bt + (size_t)(n0 + r) * K + kk0 + gs * 8, Bs + cch * 8);
      }
    }
    __syncthreads();
#pragma unroll
    for (int ks = 0; ks < 2; ++ks) {
      short8 af[4], bfr[4];
#pragma unroll
      for (int mb = 0; mb < 4; ++mb) {
        int row = wm * 64 + mb * 16 + ml;
        int gs = (ks * 4 + quad) ^ (row & 7);
        af[mb] = *(const short8*)(As + row * 64 + gs * 8);
      }
#pragma unroll
      for (int nb = 0; nb < 4; ++nb) {
        int row = wn * 64 + nb * 16 + ml;
        int gs = (ks * 4 + quad) ^ (row & 7);
        bfr[nb] = *(const short8*)(Bs + row * 64 + gs * 8);
      }
#pragma unroll
      for (int mb = 0; mb < 4; ++mb)
#pragma unroll
        for (int nb = 0; nb < 4; ++nb)
          acc[mb][nb] = MFMA16(af[mb], bfr[nb], acc[mb][nb]);
    }
  }

  // epilogue
  const int ncol0 = n0 + wn * 64;
  const int sec = ncol0 >> 10;  // 0=q 1=k 2=v
  const int h = (ncol0 & 1023) >> 6;
  if (sec < 2) {
    ushort_t* dst = (sec == 0) ? Qb : Kb;
    const float qs = (sec == 0) ? 0.18033688011112042f : 1.0f;  // log2(e)/8 into Q
#pragma unroll
    for (int mb = 0; mb < 4; ++mb) {
#pragma unroll
      for (int rg = 0; rg < 4; ++rg) {
        const int m = m0 + wm * 64 + mb * 16 + quad * 4 + rg;
        const int b = m >> 10, l = m & 1023;
        const size_t ob = ((size_t)(b * 16 + h) * 1024 + l) * 64;
#pragma unroll
        for (int nb = 0; nb < 2; ++nb) {
          const int d = nb * 16 + ml;
          float x1 = acc[mb][nb][rg] + bias[ncol0 + d];
          float x2 = acc[mb][nb + 2][rg] + bias[ncol0 + d + 32];
          float cv = cosb[(size_t)m * 64 + d] * qs;
          float sv = sinb[(size_t)m * 64 + d] * qs;
          dst[ob + d] = f2bf(x1 * cv - x2 * sv);
          dst[ob + d + 32] = f2bf(x2 * cv + x1 * sv);
        }
      }
    }
  } else {
    // V^T pi-space: addr = [bh][d][lB + 16*quad + 4*rg + mb], mb packs into b64
    const int mrow = m0 + wm * 64;
    const int b = mrow >> 10, lB = mrow & 1023;
    ushort_t* vb = Vp + ((size_t)(b * 16 + h)) * 65536 + lB;
#pragma unroll
    for (int rg = 0; rg < 4; ++rg) {
#pragma unroll
      for (int nb = 0; nb < 4; ++nb) {
        const int d = nb * 16 + ml;
        const float bs = bias[ncol0 + d];
        uint2 w;
        w.x = pack_bf2(acc[0][nb][rg] + bs, acc[1][nb][rg] + bs);
        w.y = pack_bf2(acc[2][nb][rg] + bs, acc[3][nb][rg] + bs);
        *(uint2*)(vb + (size_t)d * 1024 + 16 * quad + 4 * rg) = w;
      }
    }
  }
}

// ---------------------------------------------------------------- flash attention
// (r9 version: r2fix schedule with collapsed addressing; pass-verified r9/r12)
// 512 threads (8 waves x 32 q = 256 q/block); K and V double-buffered, ONE
// barrier per kt-step; P wave-private, aliases Q region. LDS 64KB unified:
// S[0..16K)=Q/P, [16K..24K)=K dbuf, [24K..32K)=V dbuf (ushorts). 2 blocks/CU.
__global__ __launch_bounds__(512, 4) void k_attn(const ushort_t* __restrict__ Qb,
                                                 const ushort_t* __restrict__ Kb,
                                                 const ushort_t* __restrict__ Vp,
                                                 ushort_t* __restrict__ Ob) {
  __shared__ __align__(16) ushort_t S[32768];  // 64KB unified
  const int tid = threadIdx.x, lane = tid & 63, wave = tid >> 6;
  const int quad = lane >> 4, ml = lane & 15;
  const int bh = blockIdx.x & 127, qt = blockIdx.x >> 7;  // 512 blocks, qt 0..3
  const int q0 = qt * 256;
  const size_t base = (size_t)bh * 65536;

#pragma unroll
  for (int i = 0; i < 4; ++i) {  // stage Q 256x64 once (32KB, 2048 chunks)
    int cch = i * 512 + tid;
    int r = cch >> 3, s = cch & 7, gs = s ^ (r & 7);
    load_lds16(Qb + base + (size_t)(q0 + r) * 64 + gs * 8, S + cch * 8);
  }

  // ---- staging pointers: 512 threads, 512 chunks/tile -> 1 chunk per thread
  const ushort_t* kg;
  const ushort_t* vg;
  ushort_t *kl, *vl;
  {
    int r = tid >> 3, gs = (tid & 7) ^ (r & 7);
    kg = Kb + base + (size_t)r * 64 + gs * 8;
    kl = S + 16384 + tid * 8;
    vg = Vp + base + (size_t)r * 1024 + gs * 8;
    vl = S + 24576 + tid * 8;
  }
  // prologue: K0/V0 into buf 0 (issued with Q; one drain for all)
  load_lds16(kg, kl); kg += 4096;  // next 64 key rows
  load_lds16(vg, vl); vg += 64;    // next 64 pi-cols
  __syncthreads();  // Q + K0 + V0 resident

  // ---- collapsed swizzle offsets (ushort units)
  const int gsA = quad ^ (ml & 7);            // ks=0 group
  const int gsB = (4 + quad) ^ (ml & 7);      // ks=1 group
  const int h0 = (ml >> 1) ^ (quad * 4);      // P-write group seed

  short8 qf[2][2];  // wave w reads only rows [32w,32w+32) == its P region
#pragma unroll
  for (int mb = 0; mb < 2; ++mb) {
    int rowoff = wave * 2048 + mb * 1024 + ml * 64;
    qf[mb][0] = *(const short8*)(S + rowoff + gsA * 8);
    qf[mb][1] = *(const short8*)(S + rowoff + gsB * 8);
  }
  __syncthreads();  // all qf reads done before P aliases Q region

  // ---- the 5 hoisted LDS addresses (all further indexing = immediates)
  const ushort_t* kA = S + 16384 + ml * 64 + gsA * 8;  // K ks=0 (V = +8192)
  const ushort_t* kB = S + 16384 + ml * 64 + gsB * 8;  // K ks=1
  const ushort_t* pA = S + wave * 2048 + ml * 64 + gsA * 8;  // P-read ks=0
  const ushort_t* pB = S + wave * 2048 + ml * 64 + gsB * 8;  // P-read ks=1
  ushort_t* pwl = S + wave * 2048 + quad * 256 + (ml & 1) * 4;  // P-write line

  f32x4 Oacc[2][4] = {};
  float lsum[2][4] = {};

  // Per step (CUR = kt&1, compile-time): ONE barrier, full-step latency window.
#define ATTN_STEP(CUR, LAST)                                                  \
  {                                                                           \
    if (!(LAST)) {                                                            \
      load_lds16(kg, kl + ((CUR) ^ 1) * 4096); kg += 4096;                    \
      load_lds16(vg, vl + ((CUR) ^ 1) * 4096); vg += 64;                      \
    }                                                                         \
    f32x4 Sacc[2][4] = {};                                                    \
    __builtin_amdgcn_s_setprio(1);                                            \
    _Pragma("unroll") for (int nb = 0; nb < 4; ++nb) {                        \
      short8 kfa = *(const short8*)(kA + (CUR) * 4096 + nb * 1024);           \
      short8 kfb = *(const short8*)(kB + (CUR) * 4096 + nb * 1024);           \
      Sacc[0][nb] = MFMA16(qf[0][0], kfa, Sacc[0][nb]);                       \
      Sacc[1][nb] = MFMA16(qf[1][0], kfa, Sacc[1][nb]);                       \
      Sacc[0][nb] = MFMA16(qf[0][1], kfb, Sacc[0][nb]);                       \
      Sacc[1][nb] = MFMA16(qf[1][1], kfb, Sacc[1][nb]);                       \
    }                                                                         \
    __builtin_amdgcn_s_setprio(0);                                            \
    _Pragma("unroll") for (int mb = 0; mb < 2; ++mb) {                        \
      _Pragma("unroll") for (int rg = 0; rg < 4; ++rg) {                      \
        float p0 = fast_exp2(Sacc[mb][0][rg]);                                \
        float p1 = fast_exp2(Sacc[mb][1][rg]);                                \
        float p2 = fast_exp2(Sacc[mb][2][rg]);                                \
        float p3 = fast_exp2(Sacc[mb][3][rg]);                                \
        lsum[mb][rg] += (p0 + p1) + (p2 + p3);                                \
        uint2 w;                                                              \
        w.x = pack2(p0, p1);                                                  \
        w.y = pack2(p2, p3);                                                  \
        int g8 = ((h0 ^ rg) & 7) * 8;                                         \
        *(uint2*)(pwl + mb * 1024 + rg * 64 + g8) = w;                        \
      }                                                                       \
    }                                                                         \
    __builtin_amdgcn_s_setprio(1);                                            \
    _Pragma("unroll") for (int ks = 0; ks < 2; ++ks) {                        \
      const ushort_t* pk = ks ? pB : pA;                                      \
      const ushort_t* vk = (ks ? kB : kA) + 8192 + (CUR) * 4096;              \
      short8 pf0 = *(const short8*)(pk);                                      \
      short8 pf1 = *(const short8*)(pk + 1024);                               \
      _Pragma("unroll") for (int nb = 0; nb < 4; ++nb) {                      \
        short8 vf = *(const short8*)(vk + nb * 1024);                         \
        Oacc[0][nb] = MFMA16(pf0, vf, Oacc[0][nb]);                           \
        Oacc[1][nb] = MFMA16(pf1, vf, Oacc[1][nb]);                           \
      }                                                                       \
    }                                                                         \
    __builtin_amdgcn_s_setprio(0);                                            \
    __syncthreads();                                                          \
  }

#pragma unroll 1
  for (int kt2 = 0; kt2 < 8; ++kt2) {
    ATTN_STEP(0, false)
    ATTN_STEP(1, kt2 == 7)
  }
#undef ATTN_STEP

  // epilogue: reduce lsum across the 16 lanes of each quad, normalize, store
  const int b = bh >> 4, h = bh & 15;
#pragma unroll
  for (int mb = 0; mb < 2; ++mb) {
#pragma unroll
    for (int rg = 0; rg < 4; ++rg) {
      float l = lsum[mb][rg];
      l += __shfl_xor(l, 1);
      l += __shfl_xor(l, 2);
      l += __shfl_xor(l, 4);
      l += __shfl_xor(l, 8);
      float inv = 1.f / l;
      int q = q0 + wave * 32 + mb * 16 + quad * 4 + rg;
      size_t ob = ((size_t)(b * 1024 + q)) * 1024 + h * 64;
#pragma unroll
      for (int nb = 0; nb < 4; ++nb)
        Ob[ob + nb * 16 + ml] = f2bf(Oacc[mb][nb][rg] * inv);
    }
  }
}

// ---------------------------------------------------------------- proj GEMM
// (round-7 config: 128x128, BK=128; r8's higher-occupancy retile was neutral)
// A: attn bf16 [8192][1024], Bt: wproj^T bf16 [1024][1024].
// 1D grid 512, XCD-swizzled: xcd=L&7, j=L>>3, y=xcd*8+j/8, x=j%8.
__global__ __launch_bounds__(256) void k_proj_gemm(const ushort_t* __restrict__ A,
                                                   const ushort_t* __restrict__ Bt,
                                                   const float* __restrict__ bias,
                                                   float* __restrict__ out) {
  constexpr int K = 1024;
  __shared__ __align__(16) ushort_t As[128 * 128];
  __shared__ __align__(16) ushort_t Bs[128 * 128];
  const int tid = threadIdx.x, lane = tid & 63, wave = tid >> 6;
  const int quad = lane >> 4, ml = lane & 15;
  const int wm = wave & 1, wn = wave >> 1;
  const int L = blockIdx.x, xcd = L & 7, j = L >> 3;
  const int by = xcd * 8 + (j >> 3), bx = j & 7;
  const int m0 = by * 128, n0 = bx * 128;
  f32x4 acc[4][4] = {};

  for (int kt = 0; kt < K / 128; ++kt) {
    __syncthreads();
    {
      const int kk0 = kt * 128;
#pragma unroll
      for (int i = 0; i < 8; ++i) {  // 128x128 tiles: 2048 chunks of 16B each
        int cch = i * 256 + tid;
        int r = cch >> 4, s = cch & 15, gs = s ^ (r & 15);
        load_lds16(A + (size_t)(m0 + r) * K + kk0 + gs * 8, As + cch * 8);
        load_lds16(Bt + (size_t)(n0 + r) * K + kk0 + gs * 8, Bs + cch * 8);
      }
    }
    __syncthreads();
#pragma unroll
    for (int ks = 0; ks < 4; ++ks) {
      short8 af[4], bfr[4];
#pragma unroll
      for (int mb = 0; mb < 4; ++mb) {
        int row = wm * 64 + mb * 16 + ml;
        int gs = (ks * 4 + quad) ^ (row & 15);
        af[mb] = *(const short8*)(As + row * 128 + gs * 8);
      }
#pragma unroll
      for (int nb = 0; nb < 4; ++nb) {
        int row = wn * 64 + nb * 16 + ml;
        int gs = (ks * 4 + quad) ^ (row & 15);
        bfr[nb] = *(const short8*)(Bs + row * 128 + gs * 8);
      }
#pragma unroll
      for (int mb = 0; mb < 4; ++mb)
#pragma unroll
        for (int nb = 0; nb < 4; ++nb)
          acc[mb][nb] = MFMA16(af[mb], bfr[nb], acc[mb][nb]);
    }
  }
#pragma unroll
  for (int mb = 0; mb < 4; ++mb) {
#pragma unroll
    for (int rg = 0; rg < 4; ++rg) {
      const int m = m0 + wm * 64 + mb * 16 + quad * 4 + rg;
#pragma unroll
      for (int nb = 0; nb < 4; ++nb) {
        const int n = n0 + wn * 64 + nb * 16 + ml;
        out[(size_t)m * 1024 + n] = acc[mb][nb][rg] + bias[n];
      }
    }
  }
}

// ---------------------------------------------------------------- launch
extern "C" void kernel_launch(void* const* d_in, const int* in_sizes, int n_in,
                              void* d_out, int out_size, void* d_ws, size_t ws_size,
                              hipStream_t stream) {
  const float* hs = (const float*)d_in[0];
  const float* cosb = (const float*)d_in[1];
  const float* sinb = (const float*)d_in[2];
  const float* wqkv = (const float*)d_in[3];
  const float* bqkv = (const float*)d_in[4];
  const float* wproj = (const float*)d_in[5];
  const float* bproj = (const float*)d_in[6];
  float* out = (float*)d_out;

  char* ws = (char*)d_ws;
  ushort_t* hsb = (ushort_t*)(ws);
  ushort_t* wqkvT = (ushort_t*)(ws + (16u << 20));
  ushort_t* wprojT = (ushort_t*)(ws + (22u << 20));
  ushort_t* Qb = (ushort_t*)(ws + (24u << 20));
  ushort_t* Kb = (ushort_t*)(ws + (40u << 20));
  ushort_t* Vp = (ushort_t*)(ws + (56u << 20));
  ushort_t* attnb = hsb;  // hs consumed by qkv GEMM before attention writes

  k_prep<<<5120, 256, 0, stream>>>(hs, hsb, wqkv, wqkvT, wproj, wprojT);
  k_qkv_gemm_rope<<<768, 512, 0, stream>>>(hsb, wqkvT, bqkv, cosb, sinb,
                                           Qb, Kb, Vp);
  k_attn<<<512, 512, 0, stream>>>(Qb, Kb, Vp, attnb);
  k_proj_gemm<<<512, 256, 0, stream>>>(attnb, wprojT, bproj, out);
}